// Round 3
// baseline (166.992 us; speedup 1.0000x reference)
//
#include <hip/hip_runtime.h>
#include <hip/hip_bf16.h>
#include <math.h>

// Problem constants (from reference): B=32, T=2048, H=512, D=2H=1024
constexpr int B = 32;
constexpr int T = 2048;
constexpr int H = 512;
constexpr int D = 2 * H;       // 1024
constexpr int TS1 = 32;        // T-split for hsum kernel
constexpr int NCH = 32;        // T-chunks per batch for fused kernel
constexpr int WPB = 4;         // waves per block
constexpr int NP  = NCH * WPB; // 128 online-softmax partials per batch
constexpr int RPW = T / NCH / WPB; // 16 rows per wave
constexpr int RCB = 8;         // blocks per batch for r-combine
constexpr int PPB = NP / RCB;  // 16 partials per combine block

// ---------------------------------------------------------------------------
// Kernel 0: zero hsum and r (capture-safe, no rocclr fill)
// grid = 64 blocks: first 32 zero hsum (B*D floats), rest zero r (B*D).
// ---------------------------------------------------------------------------
__global__ void k_zero(float* __restrict__ hsum, float* __restrict__ r) {
    float* p = (blockIdx.x < 32) ? hsum : r;
    const int blk = blockIdx.x & 31;
    ((float4*)p)[blk * 256 + threadIdx.x] = make_float4(0.f, 0.f, 0.f, 0.f);
}

// ---------------------------------------------------------------------------
// Kernel 1: hsum[b,d] = sum_t h[b,t,d] * mask[b,t,d & (H-1)]
// grid = B*TS1 blocks, 256 threads; each thread owns 4 consecutive d.
// ---------------------------------------------------------------------------
__global__ void k_hsum(const float* __restrict__ h,
                       const float* __restrict__ mask,
                       float* __restrict__ hsum) {
    const int b   = blockIdx.x / TS1;
    const int ts  = blockIdx.x % TS1;
    const int tid = threadIdx.x;            // 0..255
    const int d4  = tid * 4;                // 0..1020
    const int md4 = d4 & (H - 1);           // mask tiled: d mod H

    constexpr int TCH = T / TS1;            // 64 t-steps per block
    const int t0 = ts * TCH;

    const float4* hp = reinterpret_cast<const float4*>(
        h + (size_t)b * T * D + (size_t)t0 * D) + tid;
    const float4* mp = reinterpret_cast<const float4*>(
        mask + (size_t)b * T * H + (size_t)t0 * H) + (md4 >> 2);

    float4 acc = make_float4(0.f, 0.f, 0.f, 0.f);
    for (int t = 0; t < TCH; ++t) {
        float4 hv = hp[(size_t)t * (D / 4)];
        float4 mv = mp[(size_t)t * (H / 4)];
        acc.x += hv.x * mv.x;
        acc.y += hv.y * mv.y;
        acc.z += hv.z * mv.z;
        acc.w += hv.w * mv.w;
    }
    float* dst = hsum + b * D + d4;
    atomicAdd(dst + 0, acc.x);
    atomicAdd(dst + 1, acc.y);
    atomicAdd(dst + 2, acc.z);
    atomicAdd(dst + 3, acc.w);
}

// ---------------------------------------------------------------------------
// Kernel 2 (fused): single pass over lstm.
// Per wave: for its 16 rows t, compute beta[b,t] = lstm[b,t,:].hsum[b,:]
// (butterfly-reduced -> wave-uniform), then online-softmax accumulate
// racc[D], tracking running (m, s). Writes one partial (m, s, racc[1024])
// per wave.  lstm is read exactly ONCE from HBM.
// ---------------------------------------------------------------------------
__global__ void k_fused(const float* __restrict__ lstm,
                        const float* __restrict__ hsum,
                        float* __restrict__ beta,
                        float* __restrict__ pm,
                        float* __restrict__ ps,
                        float* __restrict__ pr) {
    const int b    = blockIdx.x / NCH;
    const int ch   = blockIdx.x % NCH;
    const int w    = threadIdx.x >> 6;
    const int lane = threadIdx.x & 63;
    const int pidx = ch * WPB + w;

    const float4* hp = reinterpret_cast<const float4*>(hsum + (size_t)b * D);
    float4 hv[4];
#pragma unroll
    for (int k = 0; k < 4; ++k) hv[k] = hp[lane + 64 * k];

    float m = -INFINITY, s = 0.f;
    float4 racc[4];
#pragma unroll
    for (int k = 0; k < 4; ++k) racc[k] = make_float4(0.f, 0.f, 0.f, 0.f);

    const int t0 = ch * (T / NCH);   // 64 rows per block
    for (int i = 0; i < RPW; ++i) {
        const int t = t0 + i * WPB + w;
        const float4* lp = reinterpret_cast<const float4*>(
            lstm + ((size_t)b * T + t) * D);
        float4 lv[4];
#pragma unroll
        for (int k = 0; k < 4; ++k) lv[k] = lp[lane + 64 * k];

        float acc = 0.f;
#pragma unroll
        for (int k = 0; k < 4; ++k) {
            acc += lv[k].x * hv[k].x + lv[k].y * hv[k].y +
                   lv[k].z * hv[k].z + lv[k].w * hv[k].w;
        }
#pragma unroll
        for (int o = 32; o >= 1; o >>= 1) acc += __shfl_xor(acc, o, 64);
        if (lane == 0) beta[b * T + t] = acc;

        if (acc <= m) {
            const float e = expf(acc - m);
            s += e;
#pragma unroll
            for (int k = 0; k < 4; ++k) {
                racc[k].x = fmaf(e, lv[k].x, racc[k].x);
                racc[k].y = fmaf(e, lv[k].y, racc[k].y);
                racc[k].z = fmaf(e, lv[k].z, racc[k].z);
                racc[k].w = fmaf(e, lv[k].w, racc[k].w);
            }
        } else {
            const float c = expf(m - acc);   // expf(-inf)=0 handles first row
            s = fmaf(s, c, 1.f);
#pragma unroll
            for (int k = 0; k < 4; ++k) {
                racc[k].x = fmaf(racc[k].x, c, lv[k].x);
                racc[k].y = fmaf(racc[k].y, c, lv[k].y);
                racc[k].z = fmaf(racc[k].z, c, lv[k].z);
                racc[k].w = fmaf(racc[k].w, c, lv[k].w);
            }
            m = acc;
        }
    }

    if (lane == 0) {
        pm[b * NP + pidx] = m;
        ps[b * NP + pidx] = s;
    }
    float4* prp = reinterpret_cast<float4*>(
        pr + ((size_t)(b * NP + pidx)) * D);
#pragma unroll
    for (int k = 0; k < 4; ++k) prp[lane + 64 * k] = racc[k];
}

// ---------------------------------------------------------------------------
// Kernel 3: r-combine, parallel over B*RCB blocks.
// Each block: recompute (M,S) from the 128 (pm,ps) pairs (L2-hit scalar
// loads, cheap), then weighted-sum its 16 partial accumulators and
// atomicAdd into r with exp(m_p - M)/S folded in.
// ---------------------------------------------------------------------------
__global__ void k_rcomb(const float* __restrict__ pm,
                        const float* __restrict__ ps,
                        const float* __restrict__ pr,
                        float* __restrict__ r) {
    const int b   = blockIdx.x >> 3;       // / RCB
    const int ck  = blockIdx.x & (RCB - 1);
    const int tid = threadIdx.x;

    float M = -INFINITY;
    for (int p = 0; p < NP; ++p) M = fmaxf(M, pm[b * NP + p]);
    float S = 0.f;
    for (int p = 0; p < NP; ++p) S += expf(pm[b * NP + p] - M) * ps[b * NP + p];
    const float invS = 1.f / S;

    float4 acc = make_float4(0.f, 0.f, 0.f, 0.f);
    const int p0 = ck * PPB;
    for (int p = p0; p < p0 + PPB; ++p) {
        const float wp = expf(pm[b * NP + p] - M) * invS;
        const float4 v = reinterpret_cast<const float4*>(
            pr + ((size_t)(b * NP + p)) * D)[tid];
        acc.x = fmaf(wp, v.x, acc.x);
        acc.y = fmaf(wp, v.y, acc.y);
        acc.z = fmaf(wp, v.z, acc.z);
        acc.w = fmaf(wp, v.w, acc.w);
    }
    float* dst = r + (size_t)b * D + tid * 4;
    atomicAdd(dst + 0, acc.x);
    atomicAdd(dst + 1, acc.y);
    atomicAdd(dst + 2, acc.z);
    atomicAdd(dst + 3, acc.w);
}

// ---------------------------------------------------------------------------
// Kernel 4: alpha[b,t] = exp(beta - M) / S.  One block per b.
// ---------------------------------------------------------------------------
__global__ void k_alpha(const float* __restrict__ pm,
                        const float* __restrict__ ps,
                        const float* __restrict__ beta,
                        float* __restrict__ alpha) {
    const int b   = blockIdx.x;
    const int tid = threadIdx.x;

    float M = -INFINITY;
    for (int p = 0; p < NP; ++p) M = fmaxf(M, pm[b * NP + p]);
    float S = 0.f;
    for (int p = 0; p < NP; ++p) S += expf(pm[b * NP + p] - M) * ps[b * NP + p];
    const float invS = 1.f / S;

#pragma unroll
    for (int i = 0; i < 8; ++i) {
        const int t = tid + i * 256;
        alpha[b * T + t] = expf(beta[b * T + t] - M) * invS;
    }
}

// ---------------------------------------------------------------------------
extern "C" void kernel_launch(void* const* d_in, const int* in_sizes, int n_in,
                              void* d_out, int out_size, void* d_ws, size_t ws_size,
                              hipStream_t stream) {
    const float* h    = (const float*)d_in[0];   // [B,T,D]
    const float* lstm = (const float*)d_in[1];   // [B,T,D]
    const float* mask = (const float*)d_in[2];   // [B,T,H]

    float* out   = (float*)d_out;
    float* r     = out;            // [B,1,D] -> B*D floats
    float* alpha = out + B * D;    // [B,T]

    float* hsum = (float*)d_ws;                    // B*D    = 32K floats
    float* pm   = hsum + B * D;                    // B*NP   = 4K
    float* ps   = pm + B * NP;                     // B*NP   = 4K
    float* beta = ps + B * NP;                     // B*T    = 64K
    float* pr   = beta + B * T;                    // B*NP*D = 4M floats

    k_zero <<<64,        256, 0, stream>>>(hsum, r);
    k_hsum <<<B * TS1,   256, 0, stream>>>(h, mask, hsum);
    k_fused<<<B * NCH,   256, 0, stream>>>(lstm, hsum, beta, pm, ps, pr);
    k_rcomb<<<B * RCB,   256, 0, stream>>>(pm, ps, pr, r);
    k_alpha<<<B,         256, 0, stream>>>(pm, ps, beta, alpha);
}